// Round 6
// baseline (433.290 us; speedup 1.0000x reference)
//
#include <hip/hip_runtime.h>
#include <hip/hip_cooperative_groups.h>

namespace cg = cooperative_groups;

#define BATCH 2
#define T_LEN 1024
#define D_IN  1024
#define D_ST  16
#define CHUNKS 32
#define CLEN  32                    // T_LEN / CHUNKS
#define DTILE 64
#define NTILES 1024                 // BATCH*(D_IN/DTILE)*CHUNKS
#define NRPAIR 1024                 // BATCH*T_LEN/2
#define NCHAIN4 8192                // BATCH*D_IN*4 float4-chains (4 s each)
#define GRID_FUSED 512              // 2 blocks/CU -- safe co-residency

struct ABts {
    float row0[D_IN];
    float row1[D_IN];
    alignas(16) float Bsh[2][D_ST];
};
struct Tile {
    float dt[CLEN][DTILE];
    float xc[CLEN][DTILE];
    alignas(16) float B[CLEN][D_ST];
    alignas(16) float C[CLEN][D_ST];
};
union SMu {
    ABts ab;
    Tile tile[2];       // 40960 B
};

__device__ __forceinline__ float softplus_f(float x) {
    return fmaxf(x, 0.0f) + __logf(1.0f + __expf(-fabsf(x)));
}
__device__ __forceinline__ void ld4(float* dst, const float4* src) {
    float4 v = *src; dst[0] = v.x; dst[1] = v.y; dst[2] = v.z; dst[3] = v.w;
}

// ---- Phase AB: conv+SiLU for 2 rows -> LDS + global xc; proj; dt ----
__device__ __forceinline__ void phase_ab(
    ABts& ab, int rpair, int tid,
    const float* __restrict__ x, const float* __restrict__ cw,
    const float* __restrict__ cb, const float* __restrict__ xpw,
    const float* __restrict__ dtw, const float* __restrict__ dtb,
    float* __restrict__ xcg, float* __restrict__ dtp,
    float* __restrict__ Bss, float* __restrict__ Css)
{
    const int r0g = rpair * 2;
    const int b   = r0g >> 10;
    const int t   = r0g & 1023;          // even
    const int d0  = tid * 4;
    const float* xb = x + (size_t)b * T_LEN * D_IN + d0;
    const float4 z4 = {0,0,0,0};
    float xm3[4], xm2[4], xm1[4], x00[4], xp1[4], wv[16], bb[4];
    { float4 v = (t>=3) ? *(const float4*)(xb + (size_t)(t-3)*D_IN) : z4;
      xm3[0]=v.x; xm3[1]=v.y; xm3[2]=v.z; xm3[3]=v.w; }
    { float4 v = (t>=2) ? *(const float4*)(xb + (size_t)(t-2)*D_IN) : z4;
      xm2[0]=v.x; xm2[1]=v.y; xm2[2]=v.z; xm2[3]=v.w; }
    { float4 v = (t>=1) ? *(const float4*)(xb + (size_t)(t-1)*D_IN) : z4;
      xm1[0]=v.x; xm1[1]=v.y; xm1[2]=v.z; xm1[3]=v.w; }
    ld4(x00, (const float4*)(xb + (size_t)t*D_IN));
    ld4(xp1, (const float4*)(xb + (size_t)(t+1)*D_IN));
    #pragma unroll
    for (int q = 0; q < 4; q++) ld4(&wv[q*4], &((const float4*)cw)[tid*4 + q]);
    ld4(bb, &((const float4*)cb)[tid]);

    float o0[4], o1[4];
    #pragma unroll
    for (int q = 0; q < 4; q++) {
        float a0c = fmaf(wv[q*4+0], xm3[q], fmaf(wv[q*4+1], xm2[q],
                    fmaf(wv[q*4+2], xm1[q], fmaf(wv[q*4+3], x00[q], bb[q]))));
        float a1c = fmaf(wv[q*4+0], xm2[q], fmaf(wv[q*4+1], xm1[q],
                    fmaf(wv[q*4+2], x00[q], fmaf(wv[q*4+3], xp1[q], bb[q]))));
        o0[q] = a0c / (1.0f + __expf(-a0c));
        o1[q] = a1c / (1.0f + __expf(-a1c));
    }
    float4 v0 = {o0[0],o0[1],o0[2],o0[3]};
    float4 v1 = {o1[0],o1[1],o1[2],o1[3]};
    ((float4*)(xcg + (size_t)r0g*D_IN))[tid]     = v0;
    ((float4*)(xcg + (size_t)(r0g+1)*D_IN))[tid] = v1;
    ((float4*)ab.row0)[tid] = v0;
    ((float4*)ab.row1)[tid] = v1;
    __syncthreads();

    // proj: 32 p-outputs x 8 kg lanes, rows from LDS
    const int p = tid >> 3, kg = tid & 7;
    const float4* wr = (const float4*)(xpw + (size_t)p * D_IN);
    const float4* r0 = (const float4*)ab.row0;
    const float4* r1 = (const float4*)ab.row1;
    float4 acc0 = z4, acc1 = z4;
    #pragma unroll
    for (int j = 0; j < 32; j++) {
        int idx = kg + j*8;
        float4 w = wr[idx];
        float4 a = r0[idx];
        float4 c = r1[idx];
        acc0.x = fmaf(a.x, w.x, acc0.x); acc0.y = fmaf(a.y, w.y, acc0.y);
        acc0.z = fmaf(a.z, w.z, acc0.z); acc0.w = fmaf(a.w, w.w, acc0.w);
        acc1.x = fmaf(c.x, w.x, acc1.x); acc1.y = fmaf(c.y, w.y, acc1.y);
        acc1.z = fmaf(c.z, w.z, acc1.z); acc1.w = fmaf(c.w, w.w, acc1.w);
    }
    float v0s = (acc0.x + acc0.y) + (acc0.z + acc0.w);
    float v1s = (acc1.x + acc1.y) + (acc1.z + acc1.w);
    v0s += __shfl_xor(v0s, 1); v0s += __shfl_xor(v0s, 2); v0s += __shfl_xor(v0s, 4);
    v1s += __shfl_xor(v1s, 1); v1s += __shfl_xor(v1s, 2); v1s += __shfl_xor(v1s, 4);
    __syncthreads();
    if (kg == 0) {
        if (p < D_ST) {
            Bss[(size_t)r0g*D_ST + p]     = v0s;
            Bss[(size_t)(r0g+1)*D_ST + p] = v1s;
            ab.Bsh[0][p] = v0s;
            ab.Bsh[1][p] = v1s;
        } else {
            Css[(size_t)r0g*D_ST + (p - D_ST)]     = v0s;
            Css[(size_t)(r0g+1)*D_ST + (p - D_ST)] = v1s;
        }
    }
    __syncthreads();

    const float4* B0 = (const float4*)&ab.Bsh[0][0];
    const float4* B1 = (const float4*)&ab.Bsh[1][0];
    float4 b00 = B0[0], b01 = B0[1], b02 = B0[2], b03 = B0[3];
    float4 b10 = B1[0], b11 = B1[1], b12 = B1[2], b13 = B1[3];
    #pragma unroll
    for (int jd = 0; jd < 4; jd++) {
        int d = jd*256 + tid;
        const float4* wd = (const float4*)(dtw + (size_t)d * D_ST);
        float4 q0 = wd[0], q1 = wd[1], q2 = wd[2], q3 = wd[3];
        float bias = dtb[d];
        float z0 = bias, z1 = bias;
        z0 = fmaf(b00.x,q0.x,z0); z0 = fmaf(b00.y,q0.y,z0);
        z0 = fmaf(b00.z,q0.z,z0); z0 = fmaf(b00.w,q0.w,z0);
        z0 = fmaf(b01.x,q1.x,z0); z0 = fmaf(b01.y,q1.y,z0);
        z0 = fmaf(b01.z,q1.z,z0); z0 = fmaf(b01.w,q1.w,z0);
        z0 = fmaf(b02.x,q2.x,z0); z0 = fmaf(b02.y,q2.y,z0);
        z0 = fmaf(b02.z,q2.z,z0); z0 = fmaf(b02.w,q2.w,z0);
        z0 = fmaf(b03.x,q3.x,z0); z0 = fmaf(b03.y,q3.y,z0);
        z0 = fmaf(b03.z,q3.z,z0); z0 = fmaf(b03.w,q3.w,z0);
        z1 = fmaf(b10.x,q0.x,z1); z1 = fmaf(b10.y,q0.y,z1);
        z1 = fmaf(b10.z,q0.z,z1); z1 = fmaf(b10.w,q0.w,z1);
        z1 = fmaf(b11.x,q1.x,z1); z1 = fmaf(b11.y,q1.y,z1);
        z1 = fmaf(b11.z,q1.z,z1); z1 = fmaf(b11.w,q1.w,z1);
        z1 = fmaf(b12.x,q2.x,z1); z1 = fmaf(b12.y,q2.y,z1);
        z1 = fmaf(b12.z,q2.z,z1); z1 = fmaf(b12.w,q2.w,z1);
        z1 = fmaf(b13.x,q3.x,z1); z1 = fmaf(b13.y,q3.y,z1);
        z1 = fmaf(b13.z,q3.z,z1); z1 = fmaf(b13.w,q3.w,z1);
        dtp[(size_t)r0g*D_IN + d]     = softplus_f(softplus_f(z0));
        dtp[(size_t)(r0g+1)*D_IN + d] = softplus_f(softplus_f(z1));
    }
}

// ---- stage one (chunk, dg, b) tile into LDS ----
__device__ __forceinline__ void stage_tile(
    Tile& tl, int w, int tid,
    const float* __restrict__ dtp, const float* __restrict__ xcg,
    const float* __restrict__ Bss, const float* __restrict__ Css)
{
    const int chunk = w & (CHUNKS-1);
    const int dg = (w >> 5) & 15;
    const int b  = w >> 9;
    const int t0 = chunk*CLEN, d0 = dg*DTILE;
    #pragma unroll
    for (int k = 0; k < 2; k++) {
        int fidx = tid + k*256;
        int ti = fidx >> 4, c4 = fidx & 15;
        size_t g = (size_t)(b*T_LEN + t0 + ti)*D_IN + d0;
        ((float4*)&tl.dt[ti][0])[c4] = ((const float4*)(dtp + g))[c4];
        ((float4*)&tl.xc[ti][0])[c4] = ((const float4*)(xcg + g))[c4];
    }
    if (tid < 128) {
        int ti = tid >> 2, c4 = tid & 3;
        ((float4*)&tl.B[ti][0])[c4] =
            ((const float4*)(Bss + (size_t)(b*T_LEN + t0 + ti)*D_ST))[c4];
    } else {
        int t2 = tid - 128, ti = t2 >> 2, c4 = t2 & 3;
        ((float4*)&tl.C[ti][0])[c4] =
            ((const float4*)(Css + (size_t)(b*T_LEN + t0 + ti)*D_ST))[c4];
    }
}

// ---- Phase C: chunk partials from resident tile ----
__device__ __forceinline__ void tile_partials(
    const Tile& tl, int w, int tid, float* __restrict__ Pq, float* __restrict__ Qq)
{
    const int chunk = w & 31, dg = (w>>5)&15, b = w>>9;
    const int d0 = dg*DTILE;
    const int sg = tid & 3, dl = tid >> 2;
    const float a0 = -(float)(sg*4+1), a1 = -(float)(sg*4+2);
    const float a2 = -(float)(sg*4+3), a3 = -(float)(sg*4+4);
    float h0=0,h1=0,h2=0,h3=0,p0=1,p1=1,p2=1,p3=1;
    #pragma unroll 8
    for (int i = 0; i < CLEN; i++) {
        float dt = tl.dt[i][dl], xv = tl.xc[i][dl];
        float4 bv = *((const float4*)&tl.B[i][sg*4]);
        float e0 = fmaxf(__expf(dt*a0), 1e-38f);
        float e1 = fmaxf(__expf(dt*a1), 1e-38f);
        float e2 = fmaxf(__expf(dt*a2), 1e-38f);
        float e3 = fmaxf(__expf(dt*a3), 1e-38f);
        float q0 = fmaxf(dt*bv.x*xv, 1e-38f);
        float q1 = fmaxf(dt*bv.y*xv, 1e-38f);
        float q2 = fmaxf(dt*bv.z*xv, 1e-38f);
        float q3 = fmaxf(dt*bv.w*xv, 1e-38f);
        h0 = fmaf(e0, h0, q0); p0 *= e0;
        h1 = fmaf(e1, h1, q1); p1 *= e1;
        h2 = fmaf(e2, h2, q2); p2 *= e2;
        h3 = fmaf(e3, h3, q3); p3 *= e3;
    }
    int chain = (b*D_IN + d0 + dl)*4 + sg;
    float4 P4 = {p0,p1,p2,p3}, Q4 = {h0,h1,h2,h3};
    ((float4*)Pq)[(size_t)chunk*NCHAIN4 + chain] = P4;   // [chunk][chain]: coalesced
    ((float4*)Qq)[(size_t)chunk*NCHAIN4 + chain] = Q4;
}

// ---- Phase D: serial prefix over chunks per chain ----
__device__ __forceinline__ void phase_d(
    int gtid, const float* __restrict__ Pq, const float* __restrict__ Qq,
    float* __restrict__ H0)
{
    if (gtid >= NCHAIN4) return;
    const float4* Pp = (const float4*)Pq + gtid;
    const float4* Qp = (const float4*)Qq + gtid;
    float4* Op = (float4*)H0 + gtid;
    float4 h = {0,0,0,0};
    #pragma unroll 8
    for (int c = 0; c < CHUNKS; c++) {
        float4 pp = Pp[(size_t)c*NCHAIN4], qq = Qp[(size_t)c*NCHAIN4];
        Op[(size_t)c*NCHAIN4] = h;
        h.x = fmaf(pp.x, h.x, qq.x);
        h.y = fmaf(pp.y, h.y, qq.y);
        h.z = fmaf(pp.z, h.z, qq.z);
        h.w = fmaf(pp.w, h.w, qq.w);
    }
}

// ---- Phase E: replay tile with chunk-start state; y via LDS (reuse tl.dt) ----
__device__ __forceinline__ void tile_replay(
    Tile& tl, int w, int tid, const float* __restrict__ H0,
    const float* __restrict__ Dw, float* __restrict__ y)
{
    const int chunk = w & 31, dg = (w>>5)&15, b = w>>9;
    const int t0 = chunk*CLEN, d0 = dg*DTILE;
    const int sg = tid & 3, dl = tid >> 2;
    const float a0 = -(float)(sg*4+1), a1 = -(float)(sg*4+2);
    const float a2 = -(float)(sg*4+3), a3 = -(float)(sg*4+4);
    const int chain = (b*D_IN + d0 + dl)*4 + sg;
    float4 h = ((const float4*)H0)[(size_t)chunk*NCHAIN4 + chain];
    float Dv = Dw[d0 + dl];
    #pragma unroll 8
    for (int i = 0; i < CLEN; i++) {
        float dt = tl.dt[i][dl], xv = tl.xc[i][dl];
        float4 bv = *((const float4*)&tl.B[i][sg*4]);
        float4 cv = *((const float4*)&tl.C[i][sg*4]);
        float e0 = fmaxf(__expf(dt*a0), 1e-38f);
        float e1 = fmaxf(__expf(dt*a1), 1e-38f);
        float e2 = fmaxf(__expf(dt*a2), 1e-38f);
        float e3 = fmaxf(__expf(dt*a3), 1e-38f);
        float q0 = fmaxf(dt*bv.x*xv, 1e-38f);
        float q1 = fmaxf(dt*bv.y*xv, 1e-38f);
        float q2 = fmaxf(dt*bv.z*xv, 1e-38f);
        float q3 = fmaxf(dt*bv.w*xv, 1e-38f);
        h.x = fmaf(e0, h.x, q0);
        h.y = fmaf(e1, h.y, q1);
        h.z = fmaf(e2, h.z, q2);
        h.w = fmaf(e3, h.w, q3);
        float yp = cv.x*h.x;
        yp = fmaf(cv.y, h.y, yp);
        yp = fmaf(cv.z, h.z, yp);
        yp = fmaf(cv.w, h.w, yp);
        yp += __shfl_xor(yp, 1);
        yp += __shfl_xor(yp, 2);
        if (sg == 0) tl.dt[i][dl] = fmaf(Dv, xv, yp);   // dt[i][dl] dead after read
    }
    __syncthreads();
    #pragma unroll
    for (int k = 0; k < 2; k++) {
        int fidx = tid + k*256;
        int ti = fidx >> 4, c4 = fidx & 15;
        ((float4*)(y + (size_t)(b*T_LEN + t0 + ti)*D_IN + d0))[c4] =
            ((const float4*)&tl.dt[ti][0])[c4];
    }
}

// ================= fused cooperative kernel (2 units/phase/block) =================
__global__ __launch_bounds__(256, 2) void fused_ssm_k(
    const float* __restrict__ x, const float* __restrict__ cw,
    const float* __restrict__ cb, const float* __restrict__ xpw,
    const float* __restrict__ dtw, const float* __restrict__ dtb,
    const float* __restrict__ Dw,
    float* __restrict__ xcg, float* __restrict__ dtp,
    float* __restrict__ Bss, float* __restrict__ Css,
    float* __restrict__ Pq, float* __restrict__ Qq, float* __restrict__ H0,
    float* __restrict__ y)
{
    __shared__ SMu sm;
    cg::grid_group gg = cg::this_grid();
    const int tid = threadIdx.x, blk = blockIdx.x;

    phase_ab(sm.ab, blk*2+0, tid, x, cw, cb, xpw, dtw, dtb, xcg, dtp, Bss, Css);
    __syncthreads();
    phase_ab(sm.ab, blk*2+1, tid, x, cw, cb, xpw, dtw, dtb, xcg, dtp, Bss, Css);
    __threadfence(); gg.sync();

    stage_tile(sm.tile[0], blk*2+0, tid, dtp, xcg, Bss, Css);
    stage_tile(sm.tile[1], blk*2+1, tid, dtp, xcg, Bss, Css);
    __syncthreads();
    tile_partials(sm.tile[0], blk*2+0, tid, Pq, Qq);
    tile_partials(sm.tile[1], blk*2+1, tid, Pq, Qq);
    __threadfence(); gg.sync();

    phase_d(blk*256 + tid, Pq, Qq, H0);
    __threadfence(); gg.sync();

    tile_replay(sm.tile[0], blk*2+0, tid, H0, Dw, y);
    __syncthreads();
    tile_replay(sm.tile[1], blk*2+1, tid, H0, Dw, y);
}

// ================= non-cooperative fallback =================
__global__ __launch_bounds__(256) void ab_k(
    const float* __restrict__ x, const float* __restrict__ cw,
    const float* __restrict__ cb, const float* __restrict__ xpw,
    const float* __restrict__ dtw, const float* __restrict__ dtb,
    float* __restrict__ xcg, float* __restrict__ dtp,
    float* __restrict__ Bss, float* __restrict__ Css)
{
    __shared__ ABts ab;
    phase_ab(ab, blockIdx.x, threadIdx.x, x, cw, cb, xpw, dtw, dtb, xcg, dtp, Bss, Css);
}
__global__ __launch_bounds__(256) void c_k(
    const float* __restrict__ dtp, const float* __restrict__ xcg,
    const float* __restrict__ Bss, const float* __restrict__ Css,
    float* __restrict__ Pq, float* __restrict__ Qq)
{
    __shared__ Tile tl;
    stage_tile(tl, blockIdx.x, threadIdx.x, dtp, xcg, Bss, Css);
    __syncthreads();
    tile_partials(tl, blockIdx.x, threadIdx.x, Pq, Qq);
}
__global__ __launch_bounds__(256) void d_k(
    const float* __restrict__ Pq, const float* __restrict__ Qq, float* __restrict__ H0)
{
    phase_d(blockIdx.x*256 + threadIdx.x, Pq, Qq, H0);
}
__global__ __launch_bounds__(256) void e_k(
    const float* __restrict__ dtp, const float* __restrict__ xcg,
    const float* __restrict__ Bss, const float* __restrict__ Css,
    const float* __restrict__ H0, const float* __restrict__ Dw,
    float* __restrict__ y)
{
    __shared__ Tile tl;
    stage_tile(tl, blockIdx.x, threadIdx.x, dtp, xcg, Bss, Css);
    __syncthreads();
    tile_replay(tl, blockIdx.x, threadIdx.x, H0, Dw, y);
}

extern "C" void kernel_launch(void* const* d_in, const int* in_sizes, int n_in,
                              void* d_out, int out_size, void* d_ws, size_t ws_size,
                              hipStream_t stream) {
    const float* x   = (const float*)d_in[0];
    const float* cw  = (const float*)d_in[1];
    const float* cb  = (const float*)d_in[2];
    const float* xpw = (const float*)d_in[3];
    const float* dtw = (const float*)d_in[4];
    const float* dtb = (const float*)d_in[5];
    const float* Dw  = (const float*)d_in[6];
    float* y = (float*)d_out;

    const size_t NTD = (size_t)BATCH * T_LEN * D_IN;          // 2M
    const size_t NTS = (size_t)BATCH * T_LEN * D_ST;          // 32768
    const size_t NPQ = (size_t)NCHAIN4 * CHUNKS * 4;          // 1M floats
    const size_t PAD = 1024;

    float* xc  = (float*)d_ws;
    float* dtp = xc  + NTD + PAD;
    float* Bss = dtp + NTD + PAD;
    float* Css = Bss + NTS + PAD;
    float* Pq  = Css + NTS + PAD;
    float* Qq  = Pq  + NPQ + PAD;
    float* H0  = Qq  + NPQ + PAD;

    void* args[] = { (void*)&x, (void*)&cw, (void*)&cb, (void*)&xpw,
                     (void*)&dtw, (void*)&dtb, (void*)&Dw,
                     (void*)&xc, (void*)&dtp, (void*)&Bss, (void*)&Css,
                     (void*)&Pq, (void*)&Qq, (void*)&H0, (void*)&y };
    hipError_t err = hipLaunchCooperativeKernel((void*)fused_ssm_k,
                                                dim3(GRID_FUSED), dim3(256),
                                                args, 0, stream);
    if (err != hipSuccess) {
        // fallback: same phases as separate dispatches (no co-residency needed)
        ab_k<<<NRPAIR, 256, 0, stream>>>(x, cw, cb, xpw, dtw, dtb, xc, dtp, Bss, Css);
        c_k<<<NTILES, 256, 0, stream>>>(dtp, xc, Bss, Css, Pq, Qq);
        d_k<<<NCHAIN4/256, 256, 0, stream>>>(Pq, Qq, H0);
        e_k<<<NTILES, 256, 0, stream>>>(dtp, xc, Bss, Css, H0, Dw, y);
    }
}

// Round 7
// 131.024 us; speedup vs baseline: 3.3069x; 3.3069x over previous
//
#include <hip/hip_runtime.h>

#define BATCH 2
#define T_LEN 1024
#define D_IN  1024
#define D_ST  16
#define CHUNKS 32
#define CLEN  32                    // T_LEN / CHUNKS
#define DTILE 64
#define NTILES 1024                 // BATCH*(D_IN/DTILE)*CHUNKS
#define NRPAIR 1024                 // BATCH*T_LEN/2
#define NCHAIN4 8192                // BATCH*D_IN*4 float4-chains (4 s each)

struct ABts {
    float row0[D_IN];
    float row1[D_IN];
    alignas(16) float Bsh[2][D_ST];
};
struct Tile {
    float dt[CLEN][DTILE];
    float xc[CLEN][DTILE];
    alignas(16) float B[CLEN][D_ST];
    alignas(16) float C[CLEN][D_ST];
};

__device__ __forceinline__ float softplus_f(float x) {
    return fmaxf(x, 0.0f) + __logf(1.0f + __expf(-fabsf(x)));
}
__device__ __forceinline__ void ld4(float* dst, const float4* src) {
    float4 v = *src; dst[0] = v.x; dst[1] = v.y; dst[2] = v.z; dst[3] = v.w;
}

// ---- conv+SiLU for 2 rows -> LDS + global xc; proj from LDS; dt ----
__device__ __forceinline__ void phase_ab(
    ABts& ab, int rpair, int tid,
    const float* __restrict__ x, const float* __restrict__ cw,
    const float* __restrict__ cb, const float* __restrict__ xpw,
    const float* __restrict__ dtw, const float* __restrict__ dtb,
    float* __restrict__ xcg, float* __restrict__ dtp,
    float* __restrict__ Bss, float* __restrict__ Css)
{
    const int r0g = rpair * 2;
    const int b   = r0g >> 10;
    const int t   = r0g & 1023;          // even
    const int d0  = tid * 4;
    const float* xb = x + (size_t)b * T_LEN * D_IN + d0;
    const float4 z4 = {0,0,0,0};
    float xm3[4], xm2[4], xm1[4], x00[4], xp1[4], wv[16], bb[4];
    { float4 v = (t>=3) ? *(const float4*)(xb + (size_t)(t-3)*D_IN) : z4;
      xm3[0]=v.x; xm3[1]=v.y; xm3[2]=v.z; xm3[3]=v.w; }
    { float4 v = (t>=2) ? *(const float4*)(xb + (size_t)(t-2)*D_IN) : z4;
      xm2[0]=v.x; xm2[1]=v.y; xm2[2]=v.z; xm2[3]=v.w; }
    { float4 v = (t>=1) ? *(const float4*)(xb + (size_t)(t-1)*D_IN) : z4;
      xm1[0]=v.x; xm1[1]=v.y; xm1[2]=v.z; xm1[3]=v.w; }
    ld4(x00, (const float4*)(xb + (size_t)t*D_IN));
    ld4(xp1, (const float4*)(xb + (size_t)(t+1)*D_IN));
    #pragma unroll
    for (int q = 0; q < 4; q++) ld4(&wv[q*4], &((const float4*)cw)[tid*4 + q]);
    ld4(bb, &((const float4*)cb)[tid]);

    float o0[4], o1[4];
    #pragma unroll
    for (int q = 0; q < 4; q++) {
        float a0c = fmaf(wv[q*4+0], xm3[q], fmaf(wv[q*4+1], xm2[q],
                    fmaf(wv[q*4+2], xm1[q], fmaf(wv[q*4+3], x00[q], bb[q]))));
        float a1c = fmaf(wv[q*4+0], xm2[q], fmaf(wv[q*4+1], xm1[q],
                    fmaf(wv[q*4+2], x00[q], fmaf(wv[q*4+3], xp1[q], bb[q]))));
        o0[q] = a0c / (1.0f + __expf(-a0c));
        o1[q] = a1c / (1.0f + __expf(-a1c));
    }
    float4 v0 = {o0[0],o0[1],o0[2],o0[3]};
    float4 v1 = {o1[0],o1[1],o1[2],o1[3]};
    ((float4*)(xcg + (size_t)r0g*D_IN))[tid]     = v0;
    ((float4*)(xcg + (size_t)(r0g+1)*D_IN))[tid] = v1;
    ((float4*)ab.row0)[tid] = v0;
    ((float4*)ab.row1)[tid] = v1;
    __syncthreads();

    // proj: 32 p-outputs x 8 kg lanes, rows from LDS
    const int p = tid >> 3, kg = tid & 7;
    const float4* wr = (const float4*)(xpw + (size_t)p * D_IN);
    const float4* r0 = (const float4*)ab.row0;
    const float4* r1 = (const float4*)ab.row1;
    float4 acc0 = z4, acc1 = z4;
    #pragma unroll
    for (int j = 0; j < 32; j++) {
        int idx = kg + j*8;
        float4 w = wr[idx];
        float4 a = r0[idx];
        float4 c = r1[idx];
        acc0.x = fmaf(a.x, w.x, acc0.x); acc0.y = fmaf(a.y, w.y, acc0.y);
        acc0.z = fmaf(a.z, w.z, acc0.z); acc0.w = fmaf(a.w, w.w, acc0.w);
        acc1.x = fmaf(c.x, w.x, acc1.x); acc1.y = fmaf(c.y, w.y, acc1.y);
        acc1.z = fmaf(c.z, w.z, acc1.z); acc1.w = fmaf(c.w, w.w, acc1.w);
    }
    float v0s = (acc0.x + acc0.y) + (acc0.z + acc0.w);
    float v1s = (acc1.x + acc1.y) + (acc1.z + acc1.w);
    v0s += __shfl_xor(v0s, 1); v0s += __shfl_xor(v0s, 2); v0s += __shfl_xor(v0s, 4);
    v1s += __shfl_xor(v1s, 1); v1s += __shfl_xor(v1s, 2); v1s += __shfl_xor(v1s, 4);
    __syncthreads();
    if (kg == 0) {
        if (p < D_ST) {
            Bss[(size_t)r0g*D_ST + p]     = v0s;
            Bss[(size_t)(r0g+1)*D_ST + p] = v1s;
            ab.Bsh[0][p] = v0s;
            ab.Bsh[1][p] = v1s;
        } else {
            Css[(size_t)r0g*D_ST + (p - D_ST)]     = v0s;
            Css[(size_t)(r0g+1)*D_ST + (p - D_ST)] = v1s;
        }
    }
    __syncthreads();

    const float4* B0 = (const float4*)&ab.Bsh[0][0];
    const float4* B1 = (const float4*)&ab.Bsh[1][0];
    float4 b00 = B0[0], b01 = B0[1], b02 = B0[2], b03 = B0[3];
    float4 b10 = B1[0], b11 = B1[1], b12 = B1[2], b13 = B1[3];
    #pragma unroll
    for (int jd = 0; jd < 4; jd++) {
        int d = jd*256 + tid;
        const float4* wd = (const float4*)(dtw + (size_t)d * D_ST);
        float4 q0 = wd[0], q1 = wd[1], q2 = wd[2], q3 = wd[3];
        float bias = dtb[d];
        float z0 = bias, z1 = bias;
        z0 = fmaf(b00.x,q0.x,z0); z0 = fmaf(b00.y,q0.y,z0);
        z0 = fmaf(b00.z,q0.z,z0); z0 = fmaf(b00.w,q0.w,z0);
        z0 = fmaf(b01.x,q1.x,z0); z0 = fmaf(b01.y,q1.y,z0);
        z0 = fmaf(b01.z,q1.z,z0); z0 = fmaf(b01.w,q1.w,z0);
        z0 = fmaf(b02.x,q2.x,z0); z0 = fmaf(b02.y,q2.y,z0);
        z0 = fmaf(b02.z,q2.z,z0); z0 = fmaf(b02.w,q2.w,z0);
        z0 = fmaf(b03.x,q3.x,z0); z0 = fmaf(b03.y,q3.y,z0);
        z0 = fmaf(b03.z,q3.z,z0); z0 = fmaf(b03.w,q3.w,z0);
        z1 = fmaf(b10.x,q0.x,z1); z1 = fmaf(b10.y,q0.y,z1);
        z1 = fmaf(b10.z,q0.z,z1); z1 = fmaf(b10.w,q0.w,z1);
        z1 = fmaf(b11.x,q1.x,z1); z1 = fmaf(b11.y,q1.y,z1);
        z1 = fmaf(b11.z,q1.z,z1); z1 = fmaf(b11.w,q1.w,z1);
        z1 = fmaf(b12.x,q2.x,z1); z1 = fmaf(b12.y,q2.y,z1);
        z1 = fmaf(b12.z,q2.z,z1); z1 = fmaf(b12.w,q2.w,z1);
        z1 = fmaf(b13.x,q3.x,z1); z1 = fmaf(b13.y,q3.y,z1);
        z1 = fmaf(b13.z,q3.z,z1); z1 = fmaf(b13.w,q3.w,z1);
        dtp[(size_t)r0g*D_IN + d]     = softplus_f(softplus_f(z0));
        dtp[(size_t)(r0g+1)*D_IN + d] = softplus_f(softplus_f(z1));
    }
}

// ---- stage one (chunk, dg, b) tile into LDS ----
__device__ __forceinline__ void stage_tile(
    Tile& tl, int w, int tid,
    const float* __restrict__ dtp, const float* __restrict__ xcg,
    const float* __restrict__ Bss, const float* __restrict__ Css)
{
    const int chunk = w & (CHUNKS-1);
    const int dg = (w >> 5) & 15;
    const int b  = w >> 9;
    const int t0 = chunk*CLEN, d0 = dg*DTILE;
    #pragma unroll
    for (int k = 0; k < 2; k++) {
        int fidx = tid + k*256;
        int ti = fidx >> 4, c4 = fidx & 15;
        size_t g = (size_t)(b*T_LEN + t0 + ti)*D_IN + d0;
        ((float4*)&tl.dt[ti][0])[c4] = ((const float4*)(dtp + g))[c4];
        ((float4*)&tl.xc[ti][0])[c4] = ((const float4*)(xcg + g))[c4];
    }
    if (tid < 128) {
        int ti = tid >> 2, c4 = tid & 3;
        ((float4*)&tl.B[ti][0])[c4] =
            ((const float4*)(Bss + (size_t)(b*T_LEN + t0 + ti)*D_ST))[c4];
    } else {
        int t2 = tid - 128, ti = t2 >> 2, c4 = t2 & 3;
        ((float4*)&tl.C[ti][0])[c4] =
            ((const float4*)(Css + (size_t)(b*T_LEN + t0 + ti)*D_ST))[c4];
    }
}

// ---- chunk partials from resident tile -> Pq/Qq in [chunk][chain] layout ----
__device__ __forceinline__ void tile_partials(
    const Tile& tl, int w, int tid, float* __restrict__ Pq, float* __restrict__ Qq)
{
    const int chunk = w & 31, dg = (w>>5)&15, b = w>>9;
    const int d0 = dg*DTILE;
    const int sg = tid & 3, dl = tid >> 2;
    const float a0 = -(float)(sg*4+1), a1 = -(float)(sg*4+2);
    const float a2 = -(float)(sg*4+3), a3 = -(float)(sg*4+4);
    float h0=0,h1=0,h2=0,h3=0,p0=1,p1=1,p2=1,p3=1;
    #pragma unroll 8
    for (int i = 0; i < CLEN; i++) {
        float dt = tl.dt[i][dl], xv = tl.xc[i][dl];
        float4 bv = *((const float4*)&tl.B[i][sg*4]);
        float e0 = fmaxf(__expf(dt*a0), 1e-38f);
        float e1 = fmaxf(__expf(dt*a1), 1e-38f);
        float e2 = fmaxf(__expf(dt*a2), 1e-38f);
        float e3 = fmaxf(__expf(dt*a3), 1e-38f);
        float q0 = fmaxf(dt*bv.x*xv, 1e-38f);
        float q1 = fmaxf(dt*bv.y*xv, 1e-38f);
        float q2 = fmaxf(dt*bv.z*xv, 1e-38f);
        float q3 = fmaxf(dt*bv.w*xv, 1e-38f);
        h0 = fmaf(e0, h0, q0); p0 *= e0;
        h1 = fmaf(e1, h1, q1); p1 *= e1;
        h2 = fmaf(e2, h2, q2); p2 *= e2;
        h3 = fmaf(e3, h3, q3); p3 *= e3;
    }
    int chain = (b*D_IN + d0 + dl)*4 + sg;
    float4 P4 = {p0,p1,p2,p3}, Q4 = {h0,h1,h2,h3};
    ((float4*)Pq)[(size_t)chunk*NCHAIN4 + chain] = P4;   // coalesced across lanes
    ((float4*)Qq)[(size_t)chunk*NCHAIN4 + chain] = Q4;
}

// ---- per-block chunk-prefix: h at start of `chunk` for this lane's chain ----
__device__ __forceinline__ float4 chunk_prefix(
    int chunk, int chain, const float* __restrict__ Pq, const float* __restrict__ Qq)
{
    const float4* Pp = (const float4*)Pq;
    const float4* Qp = (const float4*)Qq;
    float4 h = {0,0,0,0};
    #pragma unroll 8
    for (int c = 0; c < CHUNKS-1; c++) {
        float4 pp = Pp[(size_t)c*NCHAIN4 + chain];   // coalesced across lanes
        float4 qq = Qp[(size_t)c*NCHAIN4 + chain];
        bool v = (c < chunk);
        h.x = v ? fmaf(pp.x, h.x, qq.x) : h.x;
        h.y = v ? fmaf(pp.y, h.y, qq.y) : h.y;
        h.z = v ? fmaf(pp.z, h.z, qq.z) : h.z;
        h.w = v ? fmaf(pp.w, h.w, qq.w) : h.w;
    }
    return h;
}

// ---- replay tile with chunk-start state; y via LDS (reuse tl.dt) ----
__device__ __forceinline__ void tile_replay(
    Tile& tl, int w, int tid, float4 h,
    const float* __restrict__ Dw, float* __restrict__ y)
{
    const int chunk = w & 31, dg = (w>>5)&15, b = w>>9;
    const int t0 = chunk*CLEN, d0 = dg*DTILE;
    const int sg = tid & 3, dl = tid >> 2;
    const float a0 = -(float)(sg*4+1), a1 = -(float)(sg*4+2);
    const float a2 = -(float)(sg*4+3), a3 = -(float)(sg*4+4);
    float Dv = Dw[d0 + dl];
    #pragma unroll 8
    for (int i = 0; i < CLEN; i++) {
        float dt = tl.dt[i][dl], xv = tl.xc[i][dl];
        float4 bv = *((const float4*)&tl.B[i][sg*4]);
        float4 cv = *((const float4*)&tl.C[i][sg*4]);
        float e0 = fmaxf(__expf(dt*a0), 1e-38f);
        float e1 = fmaxf(__expf(dt*a1), 1e-38f);
        float e2 = fmaxf(__expf(dt*a2), 1e-38f);
        float e3 = fmaxf(__expf(dt*a3), 1e-38f);
        float q0 = fmaxf(dt*bv.x*xv, 1e-38f);
        float q1 = fmaxf(dt*bv.y*xv, 1e-38f);
        float q2 = fmaxf(dt*bv.z*xv, 1e-38f);
        float q3 = fmaxf(dt*bv.w*xv, 1e-38f);
        h.x = fmaf(e0, h.x, q0);
        h.y = fmaf(e1, h.y, q1);
        h.z = fmaf(e2, h.z, q2);
        h.w = fmaf(e3, h.w, q3);
        float yp = cv.x*h.x;
        yp = fmaf(cv.y, h.y, yp);
        yp = fmaf(cv.z, h.z, yp);
        yp = fmaf(cv.w, h.w, yp);
        yp += __shfl_xor(yp, 1);
        yp += __shfl_xor(yp, 2);
        if (sg == 0) tl.dt[i][dl] = fmaf(Dv, xv, yp);   // dt[i][dl] dead after read
    }
    __syncthreads();
    #pragma unroll
    for (int k = 0; k < 2; k++) {
        int fidx = tid + k*256;
        int ti = fidx >> 4, c4 = fidx & 15;
        ((float4*)(y + (size_t)(b*T_LEN + t0 + ti)*D_IN + d0))[c4] =
            ((const float4*)&tl.dt[ti][0])[c4];
    }
}

// ================= kernels =================
__global__ __launch_bounds__(256) void ab_k(
    const float* __restrict__ x, const float* __restrict__ cw,
    const float* __restrict__ cb, const float* __restrict__ xpw,
    const float* __restrict__ dtw, const float* __restrict__ dtb,
    float* __restrict__ xcg, float* __restrict__ dtp,
    float* __restrict__ Bss, float* __restrict__ Css)
{
    __shared__ ABts ab;
    phase_ab(ab, blockIdx.x, threadIdx.x, x, cw, cb, xpw, dtw, dtb, xcg, dtp, Bss, Css);
}

__global__ __launch_bounds__(256) void c_k(
    const float* __restrict__ dtp, const float* __restrict__ xcg,
    const float* __restrict__ Bss, const float* __restrict__ Css,
    float* __restrict__ Pq, float* __restrict__ Qq)
{
    __shared__ Tile tl;
    stage_tile(tl, blockIdx.x, threadIdx.x, dtp, xcg, Bss, Css);
    __syncthreads();
    tile_partials(tl, blockIdx.x, threadIdx.x, Pq, Qq);
}

__global__ __launch_bounds__(256) void e2_k(
    const float* __restrict__ dtp, const float* __restrict__ xcg,
    const float* __restrict__ Bss, const float* __restrict__ Css,
    const float* __restrict__ Pq, const float* __restrict__ Qq,
    const float* __restrict__ Dw, float* __restrict__ y)
{
    __shared__ Tile tl;
    const int w = blockIdx.x, tid = threadIdx.x;
    stage_tile(tl, w, tid, dtp, xcg, Bss, Css);
    // prefix while the staging loads land (independent of LDS)
    const int chunk = w & 31, dg = (w>>5)&15, b = w>>9;
    const int sg = tid & 3, dl = tid >> 2;
    const int chain = (b*D_IN + dg*DTILE + dl)*4 + sg;
    float4 h = chunk_prefix(chunk, chain, Pq, Qq);
    __syncthreads();
    tile_replay(tl, w, tid, h, Dw, y);
}

extern "C" void kernel_launch(void* const* d_in, const int* in_sizes, int n_in,
                              void* d_out, int out_size, void* d_ws, size_t ws_size,
                              hipStream_t stream) {
    const float* x   = (const float*)d_in[0];
    const float* cw  = (const float*)d_in[1];
    const float* cb  = (const float*)d_in[2];
    const float* xpw = (const float*)d_in[3];
    const float* dtw = (const float*)d_in[4];
    const float* dtb = (const float*)d_in[5];
    const float* Dw  = (const float*)d_in[6];
    float* y = (float*)d_out;

    const size_t NTD = (size_t)BATCH * T_LEN * D_IN;          // 2M
    const size_t NTS = (size_t)BATCH * T_LEN * D_ST;          // 32768
    const size_t NPQ = (size_t)NCHAIN4 * CHUNKS * 4;          // 1M floats
    const size_t PAD = 1024;

    float* xc  = (float*)d_ws;
    float* dtp = xc  + NTD + PAD;
    float* Bss = dtp + NTD + PAD;
    float* Css = Bss + NTS + PAD;
    float* Pq  = Css + NTS + PAD;
    float* Qq  = Pq  + NPQ + PAD;

    ab_k<<<NRPAIR, 256, 0, stream>>>(x, cw, cb, xpw, dtw, dtb, xc, dtp, Bss, Css);
    c_k<<<NTILES, 256, 0, stream>>>(dtp, xc, Bss, Css, Pq, Qq);
    e2_k<<<NTILES, 256, 0, stream>>>(dtp, xc, Bss, Css, Pq, Qq, Dw, y);
}

// Round 9
// 121.049 us; speedup vs baseline: 3.5795x; 1.0824x over previous
//
#include <hip/hip_runtime.h>

#define BATCH 2
#define T_LEN 1024
#define D_IN  1024
#define D_ST  16
#define CHUNKS 32
#define CLEN  32                    // T_LEN / CHUNKS
#define DTILE 64
#define NTILES 1024                 // BATCH*(D_IN/DTILE)*CHUNKS
#define NRPAIR 1024                 // BATCH*T_LEN/2
#define NCHAIN4 8192                // BATCH*D_IN*4 float4-chains (4 s each)

struct ABts {
    float row0[D_IN];
    float row1[D_IN];
    alignas(16) float Bsh[2][D_ST];
};
struct Tile {
    float dt[CLEN][DTILE];
    float xc[CLEN][DTILE];
    alignas(16) float B[CLEN][D_ST];
    alignas(16) float C[CLEN][D_ST];
};

__device__ __forceinline__ float softplus_f(float x) {
    return fmaxf(x, 0.0f) + __logf(1.0f + __expf(-fabsf(x)));
}
__device__ __forceinline__ void ld4(float* dst, const float4* src) {
    float4 v = *src; dst[0] = v.x; dst[1] = v.y; dst[2] = v.z; dst[3] = v.w;
}

// ---- conv+SiLU for 2 rows -> LDS + global xc; proj from LDS; dt ----
__device__ __forceinline__ void phase_ab(
    ABts& ab, int rpair, int tid,
    const float* __restrict__ x, const float* __restrict__ cw,
    const float* __restrict__ cb, const float* __restrict__ xpw,
    const float* __restrict__ dtw, const float* __restrict__ dtb,
    float* __restrict__ xcg, float* __restrict__ dtp,
    float* __restrict__ Bss, float* __restrict__ Css)
{
    const int r0g = rpair * 2;
    const int b   = r0g >> 10;
    const int t   = r0g & 1023;          // even
    const int d0  = tid * 4;
    const float* xb = x + (size_t)b * T_LEN * D_IN + d0;
    const float4 z4 = {0,0,0,0};
    float xm3[4], xm2[4], xm1[4], x00[4], xp1[4], wv[16], bb[4];
    { float4 v = (t>=3) ? *(const float4*)(xb + (size_t)(t-3)*D_IN) : z4;
      xm3[0]=v.x; xm3[1]=v.y; xm3[2]=v.z; xm3[3]=v.w; }
    { float4 v = (t>=2) ? *(const float4*)(xb + (size_t)(t-2)*D_IN) : z4;
      xm2[0]=v.x; xm2[1]=v.y; xm2[2]=v.z; xm2[3]=v.w; }
    { float4 v = (t>=1) ? *(const float4*)(xb + (size_t)(t-1)*D_IN) : z4;
      xm1[0]=v.x; xm1[1]=v.y; xm1[2]=v.z; xm1[3]=v.w; }
    ld4(x00, (const float4*)(xb + (size_t)t*D_IN));
    ld4(xp1, (const float4*)(xb + (size_t)(t+1)*D_IN));
    #pragma unroll
    for (int q = 0; q < 4; q++) ld4(&wv[q*4], &((const float4*)cw)[tid*4 + q]);
    ld4(bb, &((const float4*)cb)[tid]);

    float o0[4], o1[4];
    #pragma unroll
    for (int q = 0; q < 4; q++) {
        float a0c = fmaf(wv[q*4+0], xm3[q], fmaf(wv[q*4+1], xm2[q],
                    fmaf(wv[q*4+2], xm1[q], fmaf(wv[q*4+3], x00[q], bb[q]))));
        float a1c = fmaf(wv[q*4+0], xm2[q], fmaf(wv[q*4+1], xm1[q],
                    fmaf(wv[q*4+2], x00[q], fmaf(wv[q*4+3], xp1[q], bb[q]))));
        o0[q] = a0c / (1.0f + __expf(-a0c));
        o1[q] = a1c / (1.0f + __expf(-a1c));
    }
    float4 v0 = {o0[0],o0[1],o0[2],o0[3]};
    float4 v1 = {o1[0],o1[1],o1[2],o1[3]};
    ((float4*)(xcg + (size_t)r0g*D_IN))[tid]     = v0;
    ((float4*)(xcg + (size_t)(r0g+1)*D_IN))[tid] = v1;
    ((float4*)ab.row0)[tid] = v0;
    ((float4*)ab.row1)[tid] = v1;
    __syncthreads();

    // proj: 32 p-outputs x 8 kg lanes, rows from LDS
    const int p = tid >> 3, kg = tid & 7;
    const float4* wr = (const float4*)(xpw + (size_t)p * D_IN);
    const float4* r0 = (const float4*)ab.row0;
    const float4* r1 = (const float4*)ab.row1;
    float4 acc0 = z4, acc1 = z4;
    #pragma unroll
    for (int j = 0; j < 32; j++) {
        int idx = kg + j*8;
        float4 w = wr[idx];
        float4 a = r0[idx];
        float4 c = r1[idx];
        acc0.x = fmaf(a.x, w.x, acc0.x); acc0.y = fmaf(a.y, w.y, acc0.y);
        acc0.z = fmaf(a.z, w.z, acc0.z); acc0.w = fmaf(a.w, w.w, acc0.w);
        acc1.x = fmaf(c.x, w.x, acc1.x); acc1.y = fmaf(c.y, w.y, acc1.y);
        acc1.z = fmaf(c.z, w.z, acc1.z); acc1.w = fmaf(c.w, w.w, acc1.w);
    }
    float v0s = (acc0.x + acc0.y) + (acc0.z + acc0.w);
    float v1s = (acc1.x + acc1.y) + (acc1.z + acc1.w);
    v0s += __shfl_xor(v0s, 1); v0s += __shfl_xor(v0s, 2); v0s += __shfl_xor(v0s, 4);
    v1s += __shfl_xor(v1s, 1); v1s += __shfl_xor(v1s, 2); v1s += __shfl_xor(v1s, 4);
    __syncthreads();
    if (kg == 0) {
        if (p < D_ST) {
            Bss[(size_t)r0g*D_ST + p]     = v0s;
            Bss[(size_t)(r0g+1)*D_ST + p] = v1s;
            ab.Bsh[0][p] = v0s;
            ab.Bsh[1][p] = v1s;
        } else {
            Css[(size_t)r0g*D_ST + (p - D_ST)]     = v0s;
            Css[(size_t)(r0g+1)*D_ST + (p - D_ST)] = v1s;
        }
    }
    __syncthreads();

    const float4* B0 = (const float4*)&ab.Bsh[0][0];
    const float4* B1 = (const float4*)&ab.Bsh[1][0];
    float4 b00 = B0[0], b01 = B0[1], b02 = B0[2], b03 = B0[3];
    float4 b10 = B1[0], b11 = B1[1], b12 = B1[2], b13 = B1[3];
    #pragma unroll
    for (int jd = 0; jd < 4; jd++) {
        int d = jd*256 + tid;
        const float4* wd = (const float4*)(dtw + (size_t)d * D_ST);
        float4 q0 = wd[0], q1 = wd[1], q2 = wd[2], q3 = wd[3];
        float bias = dtb[d];
        float z0 = bias, z1 = bias;
        z0 = fmaf(b00.x,q0.x,z0); z0 = fmaf(b00.y,q0.y,z0);
        z0 = fmaf(b00.z,q0.z,z0); z0 = fmaf(b00.w,q0.w,z0);
        z0 = fmaf(b01.x,q1.x,z0); z0 = fmaf(b01.y,q1.y,z0);
        z0 = fmaf(b01.z,q1.z,z0); z0 = fmaf(b01.w,q1.w,z0);
        z0 = fmaf(b02.x,q2.x,z0); z0 = fmaf(b02.y,q2.y,z0);
        z0 = fmaf(b02.z,q2.z,z0); z0 = fmaf(b02.w,q2.w,z0);
        z0 = fmaf(b03.x,q3.x,z0); z0 = fmaf(b03.y,q3.y,z0);
        z0 = fmaf(b03.z,q3.z,z0); z0 = fmaf(b03.w,q3.w,z0);
        z1 = fmaf(b10.x,q0.x,z1); z1 = fmaf(b10.y,q0.y,z1);
        z1 = fmaf(b10.z,q0.z,z1); z1 = fmaf(b10.w,q0.w,z1);
        z1 = fmaf(b11.x,q1.x,z1); z1 = fmaf(b11.y,q1.y,z1);
        z1 = fmaf(b11.z,q1.z,z1); z1 = fmaf(b11.w,q1.w,z1);
        z1 = fmaf(b12.x,q2.x,z1); z1 = fmaf(b12.y,q2.y,z1);
        z1 = fmaf(b12.z,q2.z,z1); z1 = fmaf(b12.w,q2.w,z1);
        z1 = fmaf(b13.x,q3.x,z1); z1 = fmaf(b13.y,q3.y,z1);
        z1 = fmaf(b13.z,q3.z,z1); z1 = fmaf(b13.w,q3.w,z1);
        dtp[(size_t)r0g*D_IN + d]     = softplus_f(softplus_f(z0));
        dtp[(size_t)(r0g+1)*D_IN + d] = softplus_f(softplus_f(z1));
    }
}

// ---- stage one (chunk, dg, b) tile into LDS ----
__device__ __forceinline__ void stage_tile(
    Tile& tl, int w, int tid,
    const float* __restrict__ dtp, const float* __restrict__ xcg,
    const float* __restrict__ Bss, const float* __restrict__ Css)
{
    const int chunk = w & (CHUNKS-1);
    const int dg = (w >> 5) & 15;
    const int b  = w >> 9;
    const int t0 = chunk*CLEN, d0 = dg*DTILE;
    #pragma unroll
    for (int k = 0; k < 2; k++) {
        int fidx = tid + k*256;
        int ti = fidx >> 4, c4 = fidx & 15;
        size_t g = (size_t)(b*T_LEN + t0 + ti)*D_IN + d0;
        ((float4*)&tl.dt[ti][0])[c4] = ((const float4*)(dtp + g))[c4];
        ((float4*)&tl.xc[ti][0])[c4] = ((const float4*)(xcg + g))[c4];
    }
    if (tid < 128) {
        int ti = tid >> 2, c4 = tid & 3;
        ((float4*)&tl.B[ti][0])[c4] =
            ((const float4*)(Bss + (size_t)(b*T_LEN + t0 + ti)*D_ST))[c4];
    } else {
        int t2 = tid - 128, ti = t2 >> 2, c4 = t2 & 3;
        ((float4*)&tl.C[ti][0])[c4] =
            ((const float4*)(Css + (size_t)(b*T_LEN + t0 + ti)*D_ST))[c4];
    }
}

// ---- chunk partials from resident tile -> Pq/Qq in [chunk][chain] layout ----
__device__ __forceinline__ void tile_partials(
    const Tile& tl, int w, int tid, float* __restrict__ Pq, float* __restrict__ Qq)
{
    const int chunk = w & 31, dg = (w>>5)&15, b = w>>9;
    const int d0 = dg*DTILE;
    const int sg = tid & 3, dl = tid >> 2;
    const float a0 = -(float)(sg*4+1), a1 = -(float)(sg*4+2);
    const float a2 = -(float)(sg*4+3), a3 = -(float)(sg*4+4);
    float h0=0,h1=0,h2=0,h3=0,p0=1,p1=1,p2=1,p3=1;
    #pragma unroll 8
    for (int i = 0; i < CLEN; i++) {
        float dt = tl.dt[i][dl], xv = tl.xc[i][dl];
        float4 bv = *((const float4*)&tl.B[i][sg*4]);
        float e0 = fmaxf(__expf(dt*a0), 1e-38f);
        float e1 = fmaxf(__expf(dt*a1), 1e-38f);
        float e2 = fmaxf(__expf(dt*a2), 1e-38f);
        float e3 = fmaxf(__expf(dt*a3), 1e-38f);
        float q0 = fmaxf(dt*bv.x*xv, 1e-38f);
        float q1 = fmaxf(dt*bv.y*xv, 1e-38f);
        float q2 = fmaxf(dt*bv.z*xv, 1e-38f);
        float q3 = fmaxf(dt*bv.w*xv, 1e-38f);
        h0 = fmaf(e0, h0, q0); p0 *= e0;
        h1 = fmaf(e1, h1, q1); p1 *= e1;
        h2 = fmaf(e2, h2, q2); p2 *= e2;
        h3 = fmaf(e3, h3, q3); p3 *= e3;
    }
    int chain = (b*D_IN + d0 + dl)*4 + sg;
    float4 P4 = {p0,p1,p2,p3}, Q4 = {h0,h1,h2,h3};
    ((float4*)Pq)[(size_t)chunk*NCHAIN4 + chain] = P4;   // coalesced across lanes
    ((float4*)Qq)[(size_t)chunk*NCHAIN4 + chain] = Q4;
}

// ---- replay tile with chunk-start state; y via LDS (reuse tl.dt) ----
__device__ __forceinline__ void tile_replay(
    Tile& tl, int w, int tid, float4 h,
    const float* __restrict__ Dw, float* __restrict__ y)
{
    const int chunk = w & 31, dg = (w>>5)&15, b = w>>9;
    const int t0 = chunk*CLEN, d0 = dg*DTILE;
    const int sg = tid & 3, dl = tid >> 2;
    const float a0 = -(float)(sg*4+1), a1 = -(float)(sg*4+2);
    const float a2 = -(float)(sg*4+3), a3 = -(float)(sg*4+4);
    float Dv = Dw[d0 + dl];
    #pragma unroll 8
    for (int i = 0; i < CLEN; i++) {
        float dt = tl.dt[i][dl], xv = tl.xc[i][dl];
        float4 bv = *((const float4*)&tl.B[i][sg*4]);
        float4 cv = *((const float4*)&tl.C[i][sg*4]);
        float e0 = fmaxf(__expf(dt*a0), 1e-38f);
        float e1 = fmaxf(__expf(dt*a1), 1e-38f);
        float e2 = fmaxf(__expf(dt*a2), 1e-38f);
        float e3 = fmaxf(__expf(dt*a3), 1e-38f);
        float q0 = fmaxf(dt*bv.x*xv, 1e-38f);
        float q1 = fmaxf(dt*bv.y*xv, 1e-38f);
        float q2 = fmaxf(dt*bv.z*xv, 1e-38f);
        float q3 = fmaxf(dt*bv.w*xv, 1e-38f);
        h.x = fmaf(e0, h.x, q0);
        h.y = fmaf(e1, h.y, q1);
        h.z = fmaf(e2, h.z, q2);
        h.w = fmaf(e3, h.w, q3);
        float yp = cv.x*h.x;
        yp = fmaf(cv.y, h.y, yp);
        yp = fmaf(cv.z, h.z, yp);
        yp = fmaf(cv.w, h.w, yp);
        yp += __shfl_xor(yp, 1);
        yp += __shfl_xor(yp, 2);
        if (sg == 0) tl.dt[i][dl] = fmaf(Dv, xv, yp);   // dt[i][dl] dead after read
    }
    __syncthreads();
    #pragma unroll
    for (int k = 0; k < 2; k++) {
        int fidx = tid + k*256;
        int ti = fidx >> 4, c4 = fidx & 15;
        ((float4*)(y + (size_t)(b*T_LEN + t0 + ti)*D_IN + d0))[c4] =
            ((const float4*)&tl.dt[ti][0])[c4];
    }
}

// ================= kernels =================
// 512 blocks x 2 row-pairs: halves per-block-amortized weight (xpw/dtw) L2 traffic
__global__ __launch_bounds__(256) void ab_k(
    const float* __restrict__ x, const float* __restrict__ cw,
    const float* __restrict__ cb, const float* __restrict__ xpw,
    const float* __restrict__ dtw, const float* __restrict__ dtb,
    float* __restrict__ xcg, float* __restrict__ dtp,
    float* __restrict__ Bss, float* __restrict__ Css)
{
    __shared__ ABts ab;
    phase_ab(ab, blockIdx.x*2+0, threadIdx.x, x, cw, cb, xpw, dtw, dtb, xcg, dtp, Bss, Css);
    __syncthreads();
    phase_ab(ab, blockIdx.x*2+1, threadIdx.x, x, cw, cb, xpw, dtw, dtb, xcg, dtp, Bss, Css);
}

__global__ __launch_bounds__(256) void c_k(
    const float* __restrict__ dtp, const float* __restrict__ xcg,
    const float* __restrict__ Bss, const float* __restrict__ Css,
    float* __restrict__ Pq, float* __restrict__ Qq)
{
    __shared__ Tile tl;
    stage_tile(tl, blockIdx.x, threadIdx.x, dtp, xcg, Bss, Css);
    __syncthreads();
    tile_partials(tl, blockIdx.x, threadIdx.x, Pq, Qq);
}

// chunk-start states: each thread owns one chain, loads each P/Q exactly once.
// [chunk][chain] layout -> all loads/stores coalesced.
__global__ __launch_bounds__(256) void mid_k(
    const float* __restrict__ Pq, const float* __restrict__ Qq, float* __restrict__ H0)
{
    int chain = blockIdx.x*256 + threadIdx.x;
    const float4* Pp = (const float4*)Pq + chain;
    const float4* Qp = (const float4*)Qq + chain;
    float4* Op = (float4*)H0 + chain;
    float4 h = {0,0,0,0};
    #pragma unroll 8
    for (int c = 0; c < CHUNKS; c++) {
        float4 pp = Pp[(size_t)c*NCHAIN4], qq = Qp[(size_t)c*NCHAIN4];
        Op[(size_t)c*NCHAIN4] = h;
        h.x = fmaf(pp.x, h.x, qq.x);
        h.y = fmaf(pp.y, h.y, qq.y);
        h.z = fmaf(pp.z, h.z, qq.z);
        h.w = fmaf(pp.w, h.w, qq.w);
    }
}

__global__ __launch_bounds__(256) void e2_k(
    const float* __restrict__ dtp, const float* __restrict__ xcg,
    const float* __restrict__ Bss, const float* __restrict__ Css,
    const float* __restrict__ H0, const float* __restrict__ Dw,
    float* __restrict__ y)
{
    __shared__ Tile tl;
    const int w = blockIdx.x, tid = threadIdx.x;
    stage_tile(tl, w, tid, dtp, xcg, Bss, Css);
    const int chunk = w & 31, dg = (w>>5)&15, b = w>>9;
    const int sg = tid & 3, dl = tid >> 2;
    const int chain = (b*D_IN + dg*DTILE + dl)*4 + sg;
    float4 h = ((const float4*)H0)[(size_t)chunk*NCHAIN4 + chain];  // 16B, coalesced
    __syncthreads();
    tile_replay(tl, w, tid, h, Dw, y);
}

extern "C" void kernel_launch(void* const* d_in, const int* in_sizes, int n_in,
                              void* d_out, int out_size, void* d_ws, size_t ws_size,
                              hipStream_t stream) {
    const float* x   = (const float*)d_in[0];
    const float* cw  = (const float*)d_in[1];
    const float* cb  = (const float*)d_in[2];
    const float* xpw = (const float*)d_in[3];
    const float* dtw = (const float*)d_in[4];
    const float* dtb = (const float*)d_in[5];
    const float* Dw  = (const float*)d_in[6];
    float* y = (float*)d_out;

    const size_t NTD = (size_t)BATCH * T_LEN * D_IN;          // 2M
    const size_t NTS = (size_t)BATCH * T_LEN * D_ST;          // 32768
    const size_t NPQ = (size_t)NCHAIN4 * CHUNKS * 4;          // 1M floats
    const size_t PAD = 1024;

    float* xc  = (float*)d_ws;
    float* dtp = xc  + NTD + PAD;
    float* Bss = dtp + NTD + PAD;
    float* Css = Bss + NTS + PAD;
    float* Pq  = Css + NTS + PAD;
    float* Qq  = Pq  + NPQ + PAD;
    float* H0  = Qq  + NPQ + PAD;

    ab_k<<<NRPAIR/2, 256, 0, stream>>>(x, cw, cb, xpw, dtw, dtb, xc, dtp, Bss, Css);
    c_k<<<NTILES, 256, 0, stream>>>(dtp, xc, Bss, Css, Pq, Qq);
    mid_k<<<NCHAIN4/256, 256, 0, stream>>>(Pq, Qq, H0);
    e2_k<<<NTILES, 256, 0, stream>>>(dtp, xc, Bss, Css, H0, Dw, y);
}

// Round 10
// 114.112 us; speedup vs baseline: 3.7970x; 1.0608x over previous
//
#include <hip/hip_runtime.h>

#define BATCH 2
#define T_LEN 1024
#define D_IN  1024
#define D_ST  16
#define CHUNKS 32
#define CLEN  32                    // T_LEN / CHUNKS
#define DTILE 64
#define NTILES 1024                 // BATCH*(D_IN/DTILE)*CHUNKS
#define NCHAIN4 8192                // BATCH*D_IN*4 float4-chains (4 s each)

struct ABts {
    float rows[4][D_IN];
    alignas(16) float Bsh[4][D_ST];
};
struct Tile {
    float dt[CLEN][DTILE];
    float xc[CLEN][DTILE];
    alignas(16) float B[CLEN][D_ST];
    alignas(16) float C[CLEN][D_ST];
};

__device__ __forceinline__ float softplus_f(float x) {
    return fmaxf(x, 0.0f) + __logf(1.0f + __expf(-fabsf(x)));
}

// ---- single-pass 4-row block: conv+SiLU -> LDS+global; proj (4-row reuse); dt ----
// weights (xpw 128KB + dtw 64KB) streamed ONCE per block for 4 rows.
__device__ __forceinline__ void phase_ab4(
    ABts& ab, int blk, int tid,
    const float* __restrict__ x, const float* __restrict__ cw,
    const float* __restrict__ cb, const float* __restrict__ xpw,
    const float* __restrict__ dtw, const float* __restrict__ dtb,
    float* __restrict__ xcg, float* __restrict__ dtp,
    float* __restrict__ Bss, float* __restrict__ Css)
{
    const int r0 = blk * 4;             // 4 consecutive rows, same batch (1024%4==0)
    const int b  = r0 >> 10;
    const int t0 = r0 & 1023;
    const int d0 = tid * 4;
    const float* xb = x + (size_t)b * T_LEN * D_IN + d0;
    const float4 z4 = {0,0,0,0};

    // conv: need x rows t0-3 .. t0+3 (7 rows)
    float xr[7][4];
    #pragma unroll
    for (int j = 0; j < 7; j++) {
        int t = t0 + j - 3;
        float4 v = (t >= 0) ? *(const float4*)(xb + (size_t)t*D_IN) : z4;
        xr[j][0]=v.x; xr[j][1]=v.y; xr[j][2]=v.z; xr[j][3]=v.w;
    }
    float wv[16], bb[4];
    #pragma unroll
    for (int q = 0; q < 4; q++) {
        float4 v = ((const float4*)cw)[tid*4 + q];
        wv[q*4+0]=v.x; wv[q*4+1]=v.y; wv[q*4+2]=v.z; wv[q*4+3]=v.w;
    }
    { float4 v = ((const float4*)cb)[tid]; bb[0]=v.x; bb[1]=v.y; bb[2]=v.z; bb[3]=v.w; }

    #pragma unroll
    for (int j = 0; j < 4; j++) {       // output rows t0+j
        float o[4];
        #pragma unroll
        for (int q = 0; q < 4; q++) {
            float a = fmaf(wv[q*4+0], xr[j][q], fmaf(wv[q*4+1], xr[j+1][q],
                      fmaf(wv[q*4+2], xr[j+2][q], fmaf(wv[q*4+3], xr[j+3][q], bb[q]))));
            o[q] = a / (1.0f + __expf(-a));
        }
        float4 v = {o[0],o[1],o[2],o[3]};
        ((float4*)(xcg + (size_t)(r0+j)*D_IN))[tid] = v;
        ((float4*)ab.rows[j])[tid] = v;
    }
    __syncthreads();

    // proj: 32 p x 8 kg lanes; 4 rows amortize each weight load
    const int p = tid >> 3, kg = tid & 7;
    const float4* wr = (const float4*)(xpw + (size_t)p * D_IN);
    float4 acc[4] = {z4, z4, z4, z4};
    #pragma unroll
    for (int j = 0; j < 32; j++) {
        int idx = kg + j*8;
        float4 w = wr[idx];
        #pragma unroll
        for (int r = 0; r < 4; r++) {
            float4 a = ((const float4*)ab.rows[r])[idx];
            acc[r].x = fmaf(a.x, w.x, acc[r].x);
            acc[r].y = fmaf(a.y, w.y, acc[r].y);
            acc[r].z = fmaf(a.z, w.z, acc[r].z);
            acc[r].w = fmaf(a.w, w.w, acc[r].w);
        }
    }
    float vs[4];
    #pragma unroll
    for (int r = 0; r < 4; r++) {
        float v = (acc[r].x + acc[r].y) + (acc[r].z + acc[r].w);
        v += __shfl_xor(v, 1); v += __shfl_xor(v, 2); v += __shfl_xor(v, 4);
        vs[r] = v;
    }
    __syncthreads();
    if (kg == 0) {
        #pragma unroll
        for (int r = 0; r < 4; r++) {
            if (p < D_ST) {
                Bss[(size_t)(r0+r)*D_ST + p] = vs[r];
                ab.Bsh[r][p] = vs[r];
            } else {
                Css[(size_t)(r0+r)*D_ST + (p - D_ST)] = vs[r];
            }
        }
    }
    __syncthreads();

    // dt = sp(sp(B @ dtw^T + b)) for 4 rows per weight load
    float4 br[4][4];
    #pragma unroll
    for (int r = 0; r < 4; r++) {
        const float4* B = (const float4*)&ab.Bsh[r][0];
        br[r][0]=B[0]; br[r][1]=B[1]; br[r][2]=B[2]; br[r][3]=B[3];
    }
    #pragma unroll
    for (int jd = 0; jd < 4; jd++) {
        int d = jd*256 + tid;
        const float4* wd = (const float4*)(dtw + (size_t)d * D_ST);
        float4 q0 = wd[0], q1 = wd[1], q2 = wd[2], q3 = wd[3];
        float bias = dtb[d];
        #pragma unroll
        for (int r = 0; r < 4; r++) {
            float z = bias;
            z = fmaf(br[r][0].x,q0.x,z); z = fmaf(br[r][0].y,q0.y,z);
            z = fmaf(br[r][0].z,q0.z,z); z = fmaf(br[r][0].w,q0.w,z);
            z = fmaf(br[r][1].x,q1.x,z); z = fmaf(br[r][1].y,q1.y,z);
            z = fmaf(br[r][1].z,q1.z,z); z = fmaf(br[r][1].w,q1.w,z);
            z = fmaf(br[r][2].x,q2.x,z); z = fmaf(br[r][2].y,q2.y,z);
            z = fmaf(br[r][2].z,q2.z,z); z = fmaf(br[r][2].w,q2.w,z);
            z = fmaf(br[r][3].x,q3.x,z); z = fmaf(br[r][3].y,q3.y,z);
            z = fmaf(br[r][3].z,q3.z,z); z = fmaf(br[r][3].w,q3.w,z);
            dtp[(size_t)(r0+r)*D_IN + d] = softplus_f(softplus_f(z));
        }
    }
}

// ---- stage one (chunk, dg, b) tile into LDS ----
__device__ __forceinline__ void stage_tile(
    Tile& tl, int w, int tid,
    const float* __restrict__ dtp, const float* __restrict__ xcg,
    const float* __restrict__ Bss, const float* __restrict__ Css)
{
    const int chunk = w & (CHUNKS-1);
    const int dg = (w >> 5) & 15;
    const int b  = w >> 9;
    const int t0 = chunk*CLEN, d0 = dg*DTILE;
    #pragma unroll
    for (int k = 0; k < 2; k++) {
        int fidx = tid + k*256;
        int ti = fidx >> 4, c4 = fidx & 15;
        size_t g = (size_t)(b*T_LEN + t0 + ti)*D_IN + d0;
        ((float4*)&tl.dt[ti][0])[c4] = ((const float4*)(dtp + g))[c4];
        ((float4*)&tl.xc[ti][0])[c4] = ((const float4*)(xcg + g))[c4];
    }
    if (tid < 128) {
        int ti = tid >> 2, c4 = tid & 3;
        ((float4*)&tl.B[ti][0])[c4] =
            ((const float4*)(Bss + (size_t)(b*T_LEN + t0 + ti)*D_ST))[c4];
    } else {
        int t2 = tid - 128, ti = t2 >> 2, c4 = t2 & 3;
        ((float4*)&tl.C[ti][0])[c4] =
            ((const float4*)(Css + (size_t)(b*T_LEN + t0 + ti)*D_ST))[c4];
    }
}

// ---- single-exp power trick: e_s = exp(-s*dt) = E^s, E = exp(-dt) ----
// per-element fmax(.,1e-38) clamp preserved (matches reference clip semantics).
#define SCAN_STEP(DTV, XV, BV, E0,E1,E2V,E3V, Q0,Q1,Q2,Q3)                    \
    {                                                                          \
        float E  = __expf(-(DTV));                                             \
        float E2 = E*E, E4 = E2*E2, E8 = E4*E4;                                \
        float F  = (s1 ? E4 : 1.0f) * (s2 ? E8 : 1.0f);                        \
        float r0 = F*E, r1 = r0*E, r2 = r1*E, r3 = r2*E;                       \
        E0 = fmaxf(r0, 1e-38f); E1 = fmaxf(r1, 1e-38f);                        \
        E2V = fmaxf(r2, 1e-38f); E3V = fmaxf(r3, 1e-38f);                      \
        float dtx = (DTV)*(XV);                                                \
        Q0 = fmaxf(dtx*(BV).x, 1e-38f); Q1 = fmaxf(dtx*(BV).y, 1e-38f);        \
        Q2 = fmaxf(dtx*(BV).z, 1e-38f); Q3 = fmaxf(dtx*(BV).w, 1e-38f);        \
    }

// ---- chunk partials from resident tile -> Pq/Qq in [chunk][chain] layout ----
__device__ __forceinline__ void tile_partials(
    const Tile& tl, int w, int tid, float* __restrict__ Pq, float* __restrict__ Qq)
{
    const int chunk = w & 31, dg = (w>>5)&15, b = w>>9;
    const int d0 = dg*DTILE;
    const int sg = tid & 3, dl = tid >> 2;
    const bool s1 = sg & 1, s2 = sg & 2;
    float h0=0,h1=0,h2=0,h3=0,p0=1,p1=1,p2=1,p3=1;
    #pragma unroll 8
    for (int i = 0; i < CLEN; i++) {
        float dt = tl.dt[i][dl], xv = tl.xc[i][dl];
        float4 bv = *((const float4*)&tl.B[i][sg*4]);
        float e0,e1,e2,e3,q0,q1,q2,q3;
        SCAN_STEP(dt, xv, bv, e0,e1,e2,e3, q0,q1,q2,q3)
        h0 = fmaf(e0, h0, q0); p0 *= e0;
        h1 = fmaf(e1, h1, q1); p1 *= e1;
        h2 = fmaf(e2, h2, q2); p2 *= e2;
        h3 = fmaf(e3, h3, q3); p3 *= e3;
    }
    int chain = (b*D_IN + d0 + dl)*4 + sg;
    float4 P4 = {p0,p1,p2,p3}, Q4 = {h0,h1,h2,h3};
    ((float4*)Pq)[(size_t)chunk*NCHAIN4 + chain] = P4;   // coalesced across lanes
    ((float4*)Qq)[(size_t)chunk*NCHAIN4 + chain] = Q4;
}

// ---- replay tile with chunk-start state; y via LDS (reuse tl.dt) ----
__device__ __forceinline__ void tile_replay(
    Tile& tl, int w, int tid, float4 h,
    const float* __restrict__ Dw, float* __restrict__ y)
{
    const int chunk = w & 31, dg = (w>>5)&15, b = w>>9;
    const int t0 = chunk*CLEN, d0 = dg*DTILE;
    const int sg = tid & 3, dl = tid >> 2;
    const bool s1 = sg & 1, s2 = sg & 2;
    float Dv = Dw[d0 + dl];
    #pragma unroll 8
    for (int i = 0; i < CLEN; i++) {
        float dt = tl.dt[i][dl], xv = tl.xc[i][dl];
        float4 bv = *((const float4*)&tl.B[i][sg*4]);
        float4 cv = *((const float4*)&tl.C[i][sg*4]);
        float e0,e1,e2,e3,q0,q1,q2,q3;
        SCAN_STEP(dt, xv, bv, e0,e1,e2,e3, q0,q1,q2,q3)
        h.x = fmaf(e0, h.x, q0);
        h.y = fmaf(e1, h.y, q1);
        h.z = fmaf(e2, h.z, q2);
        h.w = fmaf(e3, h.w, q3);
        float yp = cv.x*h.x;
        yp = fmaf(cv.y, h.y, yp);
        yp = fmaf(cv.z, h.z, yp);
        yp = fmaf(cv.w, h.w, yp);
        yp += __shfl_xor(yp, 1);
        yp += __shfl_xor(yp, 2);
        if (sg == 0) tl.dt[i][dl] = fmaf(Dv, xv, yp);   // dt[i][dl] dead after read
    }
    __syncthreads();
    #pragma unroll
    for (int k = 0; k < 2; k++) {
        int fidx = tid + k*256;
        int ti = fidx >> 4, c4 = fidx & 15;
        ((float4*)(y + (size_t)(b*T_LEN + t0 + ti)*D_IN + d0))[c4] =
            ((const float4*)&tl.dt[ti][0])[c4];
    }
}

// ================= kernels =================
__global__ __launch_bounds__(256) void ab_k(
    const float* __restrict__ x, const float* __restrict__ cw,
    const float* __restrict__ cb, const float* __restrict__ xpw,
    const float* __restrict__ dtw, const float* __restrict__ dtb,
    float* __restrict__ xcg, float* __restrict__ dtp,
    float* __restrict__ Bss, float* __restrict__ Css)
{
    __shared__ ABts ab;
    phase_ab4(ab, blockIdx.x, threadIdx.x, x, cw, cb, xpw, dtw, dtb, xcg, dtp, Bss, Css);
}

__global__ __launch_bounds__(256) void c_k(
    const float* __restrict__ dtp, const float* __restrict__ xcg,
    const float* __restrict__ Bss, const float* __restrict__ Css,
    float* __restrict__ Pq, float* __restrict__ Qq)
{
    __shared__ Tile tl;
    stage_tile(tl, blockIdx.x, threadIdx.x, dtp, xcg, Bss, Css);
    __syncthreads();
    tile_partials(tl, blockIdx.x, threadIdx.x, Pq, Qq);
}

// chunk-start states: each thread owns one chain, loads each P/Q exactly once.
__global__ __launch_bounds__(256) void mid_k(
    const float* __restrict__ Pq, const float* __restrict__ Qq, float* __restrict__ H0)
{
    int chain = blockIdx.x*256 + threadIdx.x;
    const float4* Pp = (const float4*)Pq + chain;
    const float4* Qp = (const float4*)Qq + chain;
    float4* Op = (float4*)H0 + chain;
    float4 h = {0,0,0,0};
    #pragma unroll 8
    for (int c = 0; c < CHUNKS; c++) {
        float4 pp = Pp[(size_t)c*NCHAIN4], qq = Qp[(size_t)c*NCHAIN4];
        Op[(size_t)c*NCHAIN4] = h;
        h.x = fmaf(pp.x, h.x, qq.x);
        h.y = fmaf(pp.y, h.y, qq.y);
        h.z = fmaf(pp.z, h.z, qq.z);
        h.w = fmaf(pp.w, h.w, qq.w);
    }
}

__global__ __launch_bounds__(256) void e2_k(
    const float* __restrict__ dtp, const float* __restrict__ xcg,
    const float* __restrict__ Bss, const float* __restrict__ Css,
    const float* __restrict__ H0, const float* __restrict__ Dw,
    float* __restrict__ y)
{
    __shared__ Tile tl;
    const int w = blockIdx.x, tid = threadIdx.x;
    stage_tile(tl, w, tid, dtp, xcg, Bss, Css);
    const int chunk = w & 31, dg = (w>>5)&15, b = w>>9;
    const int sg = tid & 3, dl = tid >> 2;
    const int chain = (b*D_IN + dg*DTILE + dl)*4 + sg;
    float4 h = ((const float4*)H0)[(size_t)chunk*NCHAIN4 + chain];  // 16B, coalesced
    __syncthreads();
    tile_replay(tl, w, tid, h, Dw, y);
}

extern "C" void kernel_launch(void* const* d_in, const int* in_sizes, int n_in,
                              void* d_out, int out_size, void* d_ws, size_t ws_size,
                              hipStream_t stream) {
    const float* x   = (const float*)d_in[0];
    const float* cw  = (const float*)d_in[1];
    const float* cb  = (const float*)d_in[2];
    const float* xpw = (const float*)d_in[3];
    const float* dtw = (const float*)d_in[4];
    const float* dtb = (const float*)d_in[5];
    const float* Dw  = (const float*)d_in[6];
    float* y = (float*)d_out;

    const size_t NTD = (size_t)BATCH * T_LEN * D_IN;          // 2M
    const size_t NTS = (size_t)BATCH * T_LEN * D_ST;          // 32768
    const size_t NPQ = (size_t)NCHAIN4 * CHUNKS * 4;          // 1M floats
    const size_t PAD = 1024;

    float* xc  = (float*)d_ws;
    float* dtp = xc  + NTD + PAD;
    float* Bss = dtp + NTD + PAD;
    float* Css = Bss + NTS + PAD;
    float* Pq  = Css + NTS + PAD;
    float* Qq  = Pq  + NPQ + PAD;
    float* H0  = Qq  + NPQ + PAD;

    ab_k<<<(BATCH*T_LEN)/4, 256, 0, stream>>>(x, cw, cb, xpw, dtw, dtb, xc, dtp, Bss, Css);
    c_k<<<NTILES, 256, 0, stream>>>(dtp, xc, Bss, Css, Pq, Qq);
    mid_k<<<NCHAIN4/256, 256, 0, stream>>>(Pq, Qq, H0);
    e2_k<<<NTILES, 256, 0, stream>>>(dtp, xc, Bss, Css, H0, Dw, y);
}